// Round 15
// baseline (810.403 us; speedup 1.0000x reference)
//
#include <hip/hip_runtime.h>
#include <hip/hip_bf16.h>

// APPNP propagation - ROUND 15: CSC build via LDS counting sort (no
// memory-side atomics). Round 14: 804 us, of which ~260 us was two
// global-atomic phases (each 1.6M device-scope atomics = 64B line
// write-through each, WRITE_SIZE 105 MB). New build: 196 ranges of 512
// nodes; P1 per-block LDS range-histogram (38k global atomics total),
// P2 scan, P3 partition edges into range buckets (packed u64, LDS
// cursors; bucket reuses bufA - props start later), P4 one block per
// range builds row_ptr/col_idx/norm with LDS hist+scan+scatter.
// Props (10x gather, bf16 g padded to 128 B rows) unchanged from r14.
//
// Math: feat_{k+1} = 0.9 * norm * (A_T (feat_k * norm)) + 0.1 * feat_0,
// norm = clip(indeg,1)^(-0.5), indeg over dst (d_in[1]=src, d_in[2]=dst).
//
// Phases: 0 zero range counters + dtype probes | 1 range histogram |
// 2 scan rangeStart (+row_ptr[NN]) | 3 partition into buckets |
// 4 per-range CSC build | 5 g0 | 6 gather-propagate.
// Buffers: d_out = bf16 scratch + final fp32; bufA = bucket (build) then
// ping-pong g buffer (props). ws ~20.0 MB (< proven 20.8 floor).

#define NN 100000
#define EE 1600000
#define DD 50
#define GS 64
#define KK 10
#define RB 9               /* 512 nodes per range */
#define NPR 512
#define NRANGE 196         /* ceil(NN/512) */
#define EPB 8192           /* edges per partition block */
#define NPB 196            /* ceil(EE/EPB) */

__device__ __forceinline__ float feat_at(const void* f, long long i, int ft) {
    if (ft) return ((const float*)f)[i];
    unsigned int w = ((unsigned int)((const unsigned short*)f)[i]) << 16;
    return __uint_as_float(w);
}

__device__ __forceinline__ int idx_at(const void* p, int e, int is64) {
    return is64 ? (int)((const long long*)p)[e] : ((const int*)p)[e];
}

__device__ __forceinline__ float bf16_ld(const unsigned short* p, int i) {
    unsigned int w = ((unsigned int)p[i]) << 16;
    return __uint_as_float(w);
}

__device__ __forceinline__ unsigned short bf16_st(float x) {
    unsigned int u = __float_as_uint(x);
    unsigned int r = (u + 0x7FFF + ((u >> 16) & 1)) >> 16; // round-nearest-even
    return (unsigned short)r;
}

__global__ __launch_bounds__(256) void APPNPConv_62199716381208_kernel(
        const void* featp, const void* srcp, const void* dstp,
        float* norm, int* row_ptr, int* col_idx,
        int* rc, int* rs, int* rcur, int* flag,
        unsigned long long* bucket,
        const unsigned short* gin, unsigned short* gout, float* outp,
        int phase, int last) {
    __shared__ int sh[1280];   // [0..511] hist/cnt | [512..1023] excl/base | [1024..1279] scan
    const int tid = threadIdx.x;

    if (phase == 0) {
        // single block: zero range counters; probe index width + feat dtype
        if (tid < NRANGE) { rc[tid] = 0; }
        if (tid == 0) {
            const int* a = (const int*)dstp;
            int odd_or = a[1] | a[3] | a[5] | a[7] | a[9] | a[11] | a[13] | a[15];
            flag[0] = (odd_or == 0) ? 1 : 0;
            const unsigned short* w = (const unsigned short*)featp;
            int isf32 = 0;
            for (int k = 0; k < 64; ++k) {
                unsigned int b = ((unsigned int)w[k]) << 16;
                float ax = fabsf(__uint_as_float(b));
                if (!(ax < 100.0f)) isf32 = 1;
            }
            flag[1] = isf32;
        }
        return;
    }
    if (phase == 1) {
        // per-block LDS histogram of dst ranges
        if (tid < NRANGE) sh[tid] = 0;
        __syncthreads();
        const int is64 = flag[0];
        const int base_e = blockIdx.x * EPB;
        for (int k = 0; k < EPB / 256; ++k) {
            int e = base_e + k * 256 + tid;
            if (e < EE) {
                int d = idx_at(dstp, e, is64);
                atomicAdd(&sh[d >> RB], 1);
            }
        }
        __syncthreads();
        if (tid < NRANGE && sh[tid] > 0) atomicAdd(&rc[tid], sh[tid]);
        return;
    }
    if (phase == 2) {
        // single block: exclusive scan of rc -> rs; init rcur; row_ptr[NN]
        int v = (tid < NRANGE) ? rc[tid] : 0;
        sh[1024 + tid] = v;
        __syncthreads();
        for (int off = 1; off < 256; off <<= 1) {
            int x = (tid >= off) ? sh[1024 + tid - off] : 0;
            __syncthreads();
            sh[1024 + tid] += x;
            __syncthreads();
        }
        int excl = sh[1024 + tid] - v;
        if (tid < NRANGE) { rs[tid] = excl; rcur[tid] = excl; }
        if (tid == NRANGE) rs[NRANGE] = EE;
        if (tid == 0) row_ptr[NN] = EE;
        return;
    }
    if (phase == 3) {
        // partition edges into range buckets (packed (dst,src) u64)
        if (tid < NRANGE) sh[tid] = 0;
        __syncthreads();
        const int is64 = flag[0];
        const int base_e = blockIdx.x * EPB;
        for (int k = 0; k < EPB / 256; ++k) {
            int e = base_e + k * 256 + tid;
            if (e < EE) {
                int d = idx_at(dstp, e, is64);
                atomicAdd(&sh[d >> RB], 1);
            }
        }
        __syncthreads();
        if (tid < NRANGE) {
            sh[512 + tid] = (sh[tid] > 0) ? atomicAdd(&rcur[tid], sh[tid]) : 0;
            sh[1024 + tid] = 0;
        }
        __syncthreads();
        for (int k = 0; k < EPB / 256; ++k) {
            int e = base_e + k * 256 + tid;
            if (e < EE) {
                int d = idx_at(dstp, e, is64);
                int s = idx_at(srcp, e, is64);
                int r = d >> RB;
                int off = atomicAdd(&sh[1024 + r], 1);
                bucket[sh[512 + r] + off] =
                    (((unsigned long long)(unsigned int)d) << 32) | (unsigned int)s;
            }
        }
        return;
    }
    if (phase == 4) {
        // one block per range: LDS hist -> norm/row_ptr, LDS scatter -> col_idx
        const int r = blockIdx.x;
        const int nb = r << RB;
        const int ncnt = (NN - nb < NPR) ? (NN - nb) : NPR;
        const int es = rs[r];
        const int ee2 = rs[r + 1];
        sh[tid] = 0; sh[256 + tid] = 0;
        __syncthreads();
        for (int e = es + tid; e < ee2; e += 256) {
            int d = (int)(bucket[e] >> 32);
            atomicAdd(&sh[d - nb], 1);
        }
        __syncthreads();
        // pair-scan 512 bins with 256 threads
        int a = sh[2 * tid], b = sh[2 * tid + 1];
        int ps = a + b;
        sh[1024 + tid] = ps;
        __syncthreads();
        for (int off = 1; off < 256; off <<= 1) {
            int x = (tid >= off) ? sh[1024 + tid - off] : 0;
            __syncthreads();
            sh[1024 + tid] += x;
            __syncthreads();
        }
        int exclp = sh[1024 + tid] - ps;
        sh[512 + 2 * tid] = exclp;
        sh[512 + 2 * tid + 1] = exclp + a;
        __syncthreads();
        for (int l = tid; l < NPR; l += 256) {
            if (l < ncnt) {
                int dg = sh[l];
                row_ptr[nb + l] = es + sh[512 + l];
                norm[nb + l] = rsqrtf((float)(dg < 1 ? 1 : dg));
            }
        }
        __syncthreads();
        // reuse excl[] as scatter cursor
        for (int e = es + tid; e < ee2; e += 256) {
            unsigned long long pk = bucket[e];
            int d = (int)(pk >> 32);
            int s = (int)(pk & 0xffffffffULL);
            int off = atomicAdd(&sh[512 + (d - nb)], 1);
            col_idx[es + off] = s;
        }
        return;
    }
    if (phase == 5) {
        // g0 = bf16(feat * norm), padded stride GS
        int gidx = blockIdx.x * 256 + tid;
        int v = gidx >> 6;
        int d = gidx & 63;
        if (v < NN && d < DD) {
            float x = feat_at(featp, (long long)v * DD + d, flag[1]);
            gout[v * GS + d] = bf16_st(x * norm[v]);
        }
        return;
    }
    // phase 6: gather-propagate. One wave per node, lane = feature.
    {
        const int lane = tid & 63;
        const int v = (blockIdx.x << 2) + (tid >> 6);
        if (v >= NN) return;
        const int beg = row_ptr[v];
        const int end = row_ptr[v + 1];
        float s0 = 0.0f, s1 = 0.0f, s2 = 0.0f, s3 = 0.0f;
        for (int base = beg; base < end; base += 64) {
            int idx = base + lane;
            int my = (idx < end) ? col_idx[idx] : 0;
            int cnt = end - base;
            if (cnt > 64) cnt = 64;
            int j = 0;
            for (; j + 8 <= cnt; j += 8) {
                int c0 = __shfl(my, j, 64);
                int c1 = __shfl(my, j + 1, 64);
                int c2 = __shfl(my, j + 2, 64);
                int c3 = __shfl(my, j + 3, 64);
                int c4 = __shfl(my, j + 4, 64);
                int c5 = __shfl(my, j + 5, 64);
                int c6 = __shfl(my, j + 6, 64);
                int c7 = __shfl(my, j + 7, 64);
                if (lane < DD) {
                    float v0 = bf16_ld(gin, c0 * GS + lane);
                    float v1 = bf16_ld(gin, c1 * GS + lane);
                    float v2 = bf16_ld(gin, c2 * GS + lane);
                    float v3 = bf16_ld(gin, c3 * GS + lane);
                    float v4 = bf16_ld(gin, c4 * GS + lane);
                    float v5 = bf16_ld(gin, c5 * GS + lane);
                    float v6 = bf16_ld(gin, c6 * GS + lane);
                    float v7 = bf16_ld(gin, c7 * GS + lane);
                    s0 += v0 + v4;
                    s1 += v1 + v5;
                    s2 += v2 + v6;
                    s3 += v3 + v7;
                }
            }
            for (; j + 4 <= cnt; j += 4) {
                int c0 = __shfl(my, j, 64);
                int c1 = __shfl(my, j + 1, 64);
                int c2 = __shfl(my, j + 2, 64);
                int c3 = __shfl(my, j + 3, 64);
                if (lane < DD) {
                    s0 += bf16_ld(gin, c0 * GS + lane);
                    s1 += bf16_ld(gin, c1 * GS + lane);
                    s2 += bf16_ld(gin, c2 * GS + lane);
                    s3 += bf16_ld(gin, c3 * GS + lane);
                }
            }
            for (; j < cnt; ++j) {
                int c = __shfl(my, j, 64);
                if (lane < DD) s0 += bf16_ld(gin, c * GS + lane);
            }
        }
        if (lane < DD) {
            float sum = (s0 + s1) + (s2 + s3);
            float nv = norm[v];
            float f0 = feat_at(featp, (long long)v * DD + lane, flag[1]);
            float res = 0.9f * (sum * nv) + 0.1f * f0;
            if (last) outp[v * DD + lane] = res;
            else      gout[v * GS + lane] = bf16_st(res * nv);
        }
    }
}

extern "C" void kernel_launch(void* const* d_in, const int* in_sizes, int n_in,
                              void* d_out, int out_size, void* d_ws, size_t ws_size,
                              hipStream_t stream) {
    const void* featp = d_in[0];
    const void* src = d_in[1];
    const void* dst = d_in[2];
    float* outf = (float*)d_out;
    unsigned short* outb16 = (unsigned short*)d_out; // 12.8 MB bf16 scratch of 20 MB
    size_t out_bytes = (size_t)out_size * 4;
    (void)in_sizes;

    if (n_in != 3) {
        hipMemsetAsync(d_out, 0x50, out_bytes, stream);
        return;
    }

    size_t a_norm = (((size_t)NN * 4) + 255) / 256 * 256;
    size_t a_rp   = (((size_t)(NN + 1) * 4) + 255) / 256 * 256;
    size_t a_col  = (((size_t)EE * 4) + 255) / 256 * 256;
    size_t a_rng  = (((size_t)(NRANGE + 1) * 4) + 255) / 256 * 256;
    size_t a_flag = 256;
    size_t a_buf  = (((size_t)NN * GS * 2) + 255) / 256 * 256; // 12.8 MB
    size_t need = a_norm + a_rp + a_col + 3 * a_rng + a_flag + a_buf;
    if (ws_size < need) {
        hipMemsetAsync(d_out, 0x40, out_bytes, stream);
        return;
    }
    char* p = (char*)d_ws;
    float* norm   = (float*)p; p += a_norm;
    int* row_ptr  = (int*)p;   p += a_rp;
    int* col_idx  = (int*)p;   p += a_col;
    int* rc       = (int*)p;   p += a_rng;
    int* rs       = (int*)p;   p += a_rng;
    int* rcur     = (int*)p;   p += a_rng;
    int* flag     = (int*)p;   p += a_flag;
    unsigned short* bufA = (unsigned short*)p;
    unsigned long long* bucket = (unsigned long long*)bufA; // build-time reuse

    (void)hipGetLastError();

    #define LCH(grid, gi, go, ph, la) \
        APPNPConv_62199716381208_kernel<<<(grid), 256, 0, stream>>>( \
            featp, src, dst, norm, row_ptr, col_idx, rc, rs, rcur, flag, \
            bucket, (gi), (go), outf, (ph), (la))

    LCH(1, bufA, bufA, 0, 0);                     // zero counters + probes
    LCH(NPB, bufA, bufA, 1, 0);                   // range histogram
    LCH(1, bufA, bufA, 2, 0);                     // scan rangeStart
    LCH(NPB, bufA, bufA, 3, 0);                   // partition into buckets
    LCH(NRANGE, bufA, bufA, 4, 0);                // per-range CSC build
    LCH((NN * GS + 255) / 256, bufA, outb16, 5, 0); // g0 -> d_out (padded bf16)

    // it odd: d_out(bf16) -> bufA ; it even: bufA -> d_out(bf16).
    // it10 (even): gin = bufA (ws), writes FINAL fp32 into d_out. No overlap.
    for (int it = 1; it <= KK; ++it) {
        const unsigned short* gi = (it & 1) ? outb16 : bufA;
        unsigned short* go       = (it & 1) ? bufA : outb16;
        LCH(NN / 4, gi, go, 6, (it == KK) ? 1 : 0);
    }
    #undef LCH

    if (hipGetLastError() != hipSuccess) {
        hipMemsetAsync(d_out, 0xBF, out_bytes, stream);
    }
}